// Round 1
// baseline (283.016 us; speedup 1.0000x reference)
//
#include <hip/hip_runtime.h>

typedef __bf16 bf16;
typedef __bf16 bf16x4 __attribute__((ext_vector_type(4)));
typedef __bf16 bf16x8 __attribute__((ext_vector_type(8)));
typedef float f32x4 __attribute__((ext_vector_type(4)));

#define NROWS 32768   // B*S = 32*1024
#define EMBED 512
#define CONV_C 512
#define HID 1024
#define LABELS 128

__device__ inline void async16(const void* g, void* l) {
  __builtin_amdgcn_global_load_lds(
      (const __attribute__((address_space(1))) void*)g,
      (__attribute__((address_space(3))) void*)l, 16, 0, 0);
}

// ---- prep kernels ----------------------------------------------------------

// elementwise f32 -> bf16 (n multiple of 1024)
__global__ void cvt_bf16(const float* __restrict__ in, bf16* __restrict__ out, int n) {
  int i = (blockIdx.x * blockDim.x + threadIdx.x) * 4;
  if (i >= n) return;
  float4 v = *(const float4*)(in + i);
  bf16x4 o;
  o.x = (bf16)v.x; o.y = (bf16)v.y; o.z = (bf16)v.z; o.w = (bf16)v.w;
  *(bf16x4*)(out + i) = o;
}

// in [K,N] f32  ->  out [N,K] bf16 (transpose), 64x64 tiles
__global__ void transpose_cvt(const float* __restrict__ in, bf16* __restrict__ out,
                              int K, int N) {
  __shared__ float t[64][65];
  int kb = blockIdx.x * 64, nb = blockIdx.y * 64;
  for (int i = threadIdx.x; i < 4096; i += 256) {
    int r = i >> 6, c = i & 63;
    t[r][c] = in[(size_t)(kb + r) * N + nb + c];
  }
  __syncthreads();
  for (int i = threadIdx.x; i < 4096; i += 256) {
    int r = i >> 6, c = i & 63;
    out[(size_t)(nb + r) * K + kb + c] = (bf16)t[c][r];
  }
}

// embedding gather + f32->bf16: xb[rid][e] = bf16(emb[tok[rid]][e])
__global__ void gather_cvt(const int* __restrict__ tok, const float* __restrict__ emb,
                           bf16* __restrict__ xb) {
  size_t i = ((size_t)blockIdx.x * blockDim.x + threadIdx.x) * 4;
  int rid = (int)(i >> 9);       // 512 per row
  int e = (int)(i & 511);
  int t = tok[rid];
  float4 v = *(const float4*)(emb + (size_t)t * EMBED + e);
  bf16x4 o;
  o.x = (bf16)v.x; o.y = (bf16)v.y; o.z = (bf16)v.z; o.w = (bf16)v.w;
  *(bf16x4*)(xb + i) = o;
}

// ---- MFMA GEMM: C = relu(A @ Bt^T + bias) ---------------------------------
// A [M,K] bf16 row-major, Bt [N,K] bf16 row-major (i.e. B transposed),
// 128x128 block tile, 4 waves each 64x64, BK=32, mfma_f32_16x16x32_bf16.
template <bool RELU, bool OUTBF>
__global__ __launch_bounds__(256) void gemm_bt(const bf16* __restrict__ A,
                                               const bf16* __restrict__ Bt,
                                               const float* __restrict__ bias,
                                               void* __restrict__ out,
                                               int M, int N, int K) {
  __shared__ bf16 lA[128 * 32];
  __shared__ bf16 lB[128 * 32];
  const int tid = threadIdx.x;
  const int wave = tid >> 6, lane = tid & 63;
  const int m0 = blockIdx.x * 128, n0 = blockIdx.y * 128;
  const int wm = (wave & 1) * 64, wn = (wave >> 1) * 64;
  const int lrow = lane & 15, quad = lane >> 4;

  const f32x4 zero4 = {0.f, 0.f, 0.f, 0.f};
  f32x4 acc[4][4];
#pragma unroll
  for (int i = 0; i < 4; ++i)
#pragma unroll
    for (int j = 0; j < 4; ++j) acc[i][j] = zero4;

  const int slot0 = wave * 64 + lane;

  for (int k0 = 0; k0 < K; k0 += 32) {
    // stage A and B tiles: 128x32 bf16 each, 16B per lane per issue
#pragma unroll
    for (int c = 0; c < 2; ++c) {
      int slot = slot0 + c * 256;          // 16B slot id: row*4 + colslot
      int row = slot >> 2, cs = slot & 3;
      async16(A + (size_t)(m0 + row) * K + k0 + cs * 8,
              lA + (size_t)(wave * 64 + c * 256) * 8);
      async16(Bt + (size_t)(n0 + row) * K + k0 + cs * 8,
              lB + (size_t)(wave * 64 + c * 256) * 8);
    }
    __syncthreads();

    bf16x8 a[4], b[4];
#pragma unroll
    for (int t = 0; t < 4; ++t) {
      a[t] = *(const bf16x8*)(lA + (wm + t * 16 + lrow) * 32 + quad * 8);
      b[t] = *(const bf16x8*)(lB + (wn + t * 16 + lrow) * 32 + quad * 8);
    }
#pragma unroll
    for (int mi = 0; mi < 4; ++mi)
#pragma unroll
      for (int ni = 0; ni < 4; ++ni)
        acc[mi][ni] =
            __builtin_amdgcn_mfma_f32_16x16x32_bf16(a[mi], b[ni], acc[mi][ni], 0, 0, 0);
    __syncthreads();
  }

  // epilogue: bias + relu + store. C/D map: col=lane&15, row=quad*4+reg
#pragma unroll
  for (int mi = 0; mi < 4; ++mi) {
#pragma unroll
    for (int ni = 0; ni < 4; ++ni) {
      int col = n0 + wn + ni * 16 + lrow;
      float bv = bias[col];
#pragma unroll
      for (int r = 0; r < 4; ++r) {
        int row = m0 + wm + mi * 16 + quad * 4 + r;
        float v = acc[mi][ni][r] + bv;
        if (RELU) v = v > 0.f ? v : 0.f;
        if (OUTBF)
          ((bf16*)out)[(size_t)row * N + col] = (bf16)v;
        else
          ((float*)out)[(size_t)row * N + col] = v;
      }
    }
  }
}

// ---- launcher --------------------------------------------------------------

extern "C" void kernel_launch(void* const* d_in, const int* in_sizes, int n_in,
                              void* d_out, int out_size, void* d_ws, size_t ws_size,
                              hipStream_t stream) {
  const int* tok = (const int*)d_in[0];
  const float* emb = (const float*)d_in[1];
  const float* conv_w = (const float*)d_in[2];  // [512,512] already [N,K]
  const float* conv_b = (const float*)d_in[3];
  const float* w1 = (const float*)d_in[4];      // [512,1024] = [K,N]
  const float* b1 = (const float*)d_in[5];
  const float* w2 = (const float*)d_in[6];      // [1024,128] = [K,N]
  const float* b2 = (const float*)d_in[7];
  float* out = (float*)d_out;

  char* ws = (char*)d_ws;
  bf16* wt_conv = (bf16*)(ws);                         // 512 KB
  bf16* wt1 = (bf16*)(ws + 524288);                    // 1 MB   [1024,512]
  bf16* wt2 = (bf16*)(ws + 1572864);                   // 256 KB [128,1024]
  bf16* xb = (bf16*)(ws + 1835008);                    // 32 MB  [32768,512]
  bf16* h = (bf16*)(ws + 1835008 + 33554432);          // 32 MB  [32768,512]
  bf16* z = (bf16*)(ws + 1835008 + 2 * 33554432);      // 64 MB  [32768,1024]

  // weight prep
  hipLaunchKernelGGL(cvt_bf16, dim3(256), dim3(256), 0, stream,
                     conv_w, wt_conv, CONV_C * EMBED);
  hipLaunchKernelGGL(transpose_cvt, dim3(8, 16), dim3(256), 0, stream,
                     w1, wt1, CONV_C, HID);
  hipLaunchKernelGGL(transpose_cvt, dim3(16, 2), dim3(256), 0, stream,
                     w2, wt2, HID, LABELS);
  // embedding gather + convert
  hipLaunchKernelGGL(gather_cvt, dim3(16384), dim3(256), 0, stream, tok, emb, xb);

  // layer 1: h = relu(xb @ conv_w^T + conv_b)   [32768,512]
  hipLaunchKernelGGL((gemm_bt<true, true>), dim3(NROWS / 128, CONV_C / 128), dim3(256),
                     0, stream, xb, wt_conv, conv_b, (void*)h, NROWS, CONV_C, EMBED);
  // layer 2: z = relu(h @ w1 + b1)              [32768,1024]
  hipLaunchKernelGGL((gemm_bt<true, true>), dim3(NROWS / 128, HID / 128), dim3(256),
                     0, stream, h, wt1, b1, (void*)z, NROWS, HID, CONV_C);
  // layer 3: out = z @ w2 + b2                  [32768,128] f32
  hipLaunchKernelGGL((gemm_bt<false, false>), dim3(NROWS / 128, LABELS / 128), dim3(256),
                     0, stream, z, wt2, b2, (void*)out, NROWS, LABELS, HID);
}